// Round 2
// baseline (568.738 us; speedup 1.0000x reference)
//
#include <hip/hip_runtime.h>
#include <math.h>

// Problem constants
#define Bn   8
#define Cn   128
#define Hn   64
#define Wn   64
#define HWn  4096
#define Un   8
#define Ln   10
#define HIDn 128

// d_out layout (float offsets): final, cls_logits, l2_reg, top_i, lb_loss
#define OUT_FINAL 0
#define OUT_CLS   4194304
#define OUT_L2    4194384
#define OUT_TOPI  4194385
#define OUT_LB    4194401

// ws layout (float offsets) — total 16416 floats = 64.2 KB
#define WS_POOLED 0                      // [1024]        pooled[b][c]
#define WS_STR    1024                   // [1024*5]      S,R0,R63,C0,C63 per (b,cin)
#define WS_W9     (WS_STR + 5120)        // [8*128*9]     sum_cout w[u][cout][cin][tap]
#define WS_TOPI   (WS_W9 + 9216)         // int[16]
#define WS_GSEL   (WS_TOPI + 16)         // [16]          gate of selected units
#define WS_BIASC  (WS_GSEL + 16)         // [1024]        sum_u gate[b][u]*conv_b[u*C+c]

// JAX >= 0.4.36 defaults jax_threefry_partitionable=True. Flip to 0 for legacy.
#define NOISE_PARTITIONABLE 1

// ---------------- jax threefry2x32 noise (key=42, shape (8,8)) --------------
__device__ __forceinline__ unsigned rotl32(unsigned x, int d) {
    return (x << d) | (x >> (32 - d));
}

__device__ __forceinline__ void threefry2x32(unsigned k1, unsigned k2,
                                             unsigned c0, unsigned c1,
                                             unsigned* o0, unsigned* o1) {
    unsigned ks0 = k1, ks1 = k2, ks2 = k1 ^ k2 ^ 0x1BD11BDAu;
    unsigned ksa[3] = {ks0, ks1, ks2};
    const int rot[2][4] = {{13, 15, 26, 6}, {17, 29, 16, 24}};
    unsigned x0 = c0 + ks0, x1 = c1 + ks1;
    #pragma unroll
    for (int s = 0; s < 5; ++s) {
        #pragma unroll
        for (int q = 0; q < 4; ++q) {
            x0 += x1;
            x1 = rotl32(x1, rot[s & 1][q]);
            x1 ^= x0;
        }
        x0 += ksa[(s + 1) % 3];
        x1 += ksa[(s + 2) % 3] + (unsigned)(s + 1);
    }
    *o0 = x0;
    *o1 = x1;
}

__device__ float jax_noise_elem(int i) {
    unsigned o0, o1, bits;
#if NOISE_PARTITIONABLE
    // per-element 64-bit counter (hi=0, lo=i); bits = out0 ^ out1
    threefry2x32(0u, 42u, 0u, (unsigned)i, &o0, &o1);
    bits = o0 ^ o1;
#else
    // legacy: counts=iota(64) split in halves; out0 for i<32, out1 else
    {
        int second = (i >= 32);
        unsigned j = (unsigned)(second ? i - 32 : i);
        threefry2x32(0u, 42u, j, j + 32u, &o0, &o1);
        bits = second ? o1 : o0;
    }
#endif
    unsigned fb = (bits >> 9) | 0x3f800000u;
    float f = __uint_as_float(fb) - 1.0f;              // [0,1)
    const float lo = __uint_as_float(0xBF7FFFFFu);     // nextafterf(-1,0)
    float u = f * (1.0f - lo) + lo;                    // (1-lo) rounds to 2.0f; f*2 exact
    u = fmaxf(lo, u);
    // XLA ErfInv32 (Giles polynomial), w = -log1p(-u^2)
    float w = -log1pf(-u * u);
    float p;
    if (w < 5.0f) {
        w = w - 2.5f;
        p = 2.81022636e-08f;
        p = fmaf(p, w, 3.43273939e-07f);
        p = fmaf(p, w, -3.5233877e-06f);
        p = fmaf(p, w, -4.39150654e-06f);
        p = fmaf(p, w, 0.00021858087f);
        p = fmaf(p, w, -0.00125372503f);
        p = fmaf(p, w, -0.00417768164f);
        p = fmaf(p, w, 0.246640727f);
        p = fmaf(p, w, 1.50140941f);
    } else {
        w = sqrtf(w) - 3.0f;
        p = -0.000200214257f;
        p = fmaf(p, w, 0.000100950558f);
        p = fmaf(p, w, 0.00134934322f);
        p = fmaf(p, w, -0.00367342844f);
        p = fmaf(p, w, 0.00573950773f);
        p = fmaf(p, w, -0.0076224613f);
        p = fmaf(p, w, 0.00943887047f);
        p = fmaf(p, w, 1.00167406f);
        p = fmaf(p, w, 2.83297682f);
    }
    float n = 1.41421356237309515f * (p * u);  // sqrt(2)*erfinv(u)
    return n * 0.01f;
}

// -------- kernel 1: avg pool + border strips per (b,cin) --------------------
__global__ __launch_bounds__(256) void pool_strips_kernel(const float* __restrict__ x,
                                                          float* __restrict__ ws) {
    int bc = blockIdx.x;  // b*C + cin, 0..1023
    int tid = threadIdx.x;
    const float4* p4 = (const float4*)(x + (size_t)bc * HWn);
    float S = 0.f, R0 = 0.f, R63 = 0.f, C0 = 0.f, C63 = 0.f;
    #pragma unroll
    for (int it = 0; it < 4; ++it) {
        int i = tid + it * 256;         // float4 index; row = i/16 (16 float4/row)
        float4 v = p4[i];
        float s4 = v.x + v.y + v.z + v.w;
        S += s4;
        if (i < 16) R0 += s4;
        if (i >= 1008) R63 += s4;
        if ((i & 15) == 0) C0 += v.x;
        if ((i & 15) == 15) C63 += v.w;
    }
    __shared__ float red[256];
    float vals[5] = {S, R0, R63, C0, C63};
    float outv[5];
    for (int s = 0; s < 5; ++s) {
        __syncthreads();
        red[tid] = vals[s];
        __syncthreads();
        for (int off = 128; off > 0; off >>= 1) {
            if (tid < off) red[tid] += red[tid + off];
            __syncthreads();
        }
        outv[s] = red[0];
    }
    if (tid == 0) {
        ws[WS_POOLED + bc] = outv[0] * (1.0f / HWn);
        float* st = ws + WS_STR + bc * 5;
        st[0] = outv[0]; st[1] = outv[1]; st[2] = outv[2];
        st[3] = outv[3]; st[4] = outv[4];
    }
}

// -------- kernel 2: W9sum[u][cin][tap] = sum_cout conv_w -------------------
__global__ __launch_bounds__(256) void w9sum_kernel(const float* __restrict__ cw,
                                                    float* __restrict__ ws) {
    int t = blockIdx.x * 256 + threadIdx.x;  // 36*256 = 9216 exactly
    int u = t / 1152, rem = t - u * 1152;    // rem = cin*9 + tap
    const float* p = cw + (size_t)u * 128 * 1152 + rem;
    float s = 0.f;
    for (int cout = 0; cout < 128; ++cout) s += p[(size_t)cout * 1152];
    ws[WS_W9 + t] = s;
}

// -------- block sum-of-squares helper --------------------------------------
__device__ float block_sumsq(const float* __restrict__ p, int n, float* red) {
    int tid = threadIdx.x;
    float s = 0.f;
    for (int i = tid; i < n; i += 256) { float v = p[i]; s = fmaf(v, v, s); }
    __syncthreads();
    red[tid] = s;
    __syncthreads();
    for (int off = 128; off > 0; off >>= 1) {
        if (tid < off) red[tid] += red[tid + off];
        __syncthreads();
    }
    return red[0];
}

// -------- kernel 3: router (MLP, noise, topk, l2, lb) ----------------------
__global__ __launch_bounds__(256) void router_kernel(
    const float* __restrict__ W1, const float* __restrict__ b1,
    const float* __restrict__ W2, const float* __restrict__ b2,
    const float* __restrict__ W3, const float* __restrict__ b3,
    const float* __restrict__ W4, const float* __restrict__ b4,
    const float* __restrict__ Wu, const float* __restrict__ bu,
    const float* __restrict__ Wc, const float* __restrict__ bc,
    float* __restrict__ ws, float* __restrict__ out) {
    __shared__ float pooled[Bn * Cn];
    __shared__ float h1[Bn * HIDn];
    __shared__ float h2[Bn * HIDn];
    __shared__ float h3[Bn * 64];
    __shared__ float feat[Bn * 64];
    __shared__ float scores[Bn * Un];
    __shared__ float noise[64];
    __shared__ float red[256];
    __shared__ int topi[Bn * 2];
    int tid = threadIdx.x;

    for (int i = tid; i < Bn * Cn; i += 256) pooled[i] = ws[WS_POOLED + i];
    __syncthreads();

    for (int i = tid; i < Bn * HIDn; i += 256) {
        int b = i / HIDn, j = i % HIDn;
        float s = b1[j];
        const float* wr = W1 + j * Cn;
        for (int k = 0; k < Cn; ++k) s = fmaf(pooled[b * Cn + k], wr[k], s);
        h1[i] = fmaxf(s, 0.f);
    }
    __syncthreads();
    for (int i = tid; i < Bn * HIDn; i += 256) {
        int b = i / HIDn, j = i % HIDn;
        float s = b2[j];
        const float* wr = W2 + j * HIDn;
        for (int k = 0; k < HIDn; ++k) s = fmaf(h1[b * HIDn + k], wr[k], s);
        h2[i] = fmaxf(s, 0.f);
    }
    __syncthreads();
    for (int i = tid; i < Bn * 64; i += 256) {
        int b = i / 64, j = i % 64;
        float s = b3[j];
        const float* wr = W3 + j * HIDn;
        for (int k = 0; k < HIDn; ++k) s = fmaf(h2[b * HIDn + k], wr[k], s);
        h3[i] = fmaxf(s, 0.f);
    }
    __syncthreads();
    for (int i = tid; i < Bn * 64; i += 256) {
        int b = i / 64, j = i % 64;
        float s = b4[j];
        const float* wr = W4 + j * 64;
        for (int k = 0; k < 64; ++k) s = fmaf(h3[b * 64 + k], wr[k], s);
        feat[i] = s;
    }
    __syncthreads();
    if (tid < 64) noise[tid] = jax_noise_elem(tid);
    if (tid < Bn * Un) {
        int b = tid / Un, u = tid % Un;
        float s = bu[u];
        const float* wr = Wu + u * 64;
        for (int k = 0; k < 64; ++k) s = fmaf(feat[b * 64 + k], wr[k], s);
        scores[tid] = s;
    }
    for (int i = tid; i < Bn * Ln; i += 256) {
        int b = i / Ln, j = i % Ln;
        float s = bc[j];
        const float* wr = Wc + j * 64;
        for (int k = 0; k < 64; ++k) s = fmaf(feat[b * 64 + k], wr[k], s);
        out[OUT_CLS + i] = s;
    }
    __syncthreads();
    if (tid < Bn * Un) scores[tid] += noise[tid];
    __syncthreads();
    if (tid < Bn) {
        int b = tid;
        float best = -1e30f; int bi = 0;
        for (int u = 0; u < Un; ++u) {
            float v = scores[b * Un + u];
            if (v > best) { best = v; bi = u; }
        }
        float best2 = -1e30f; int bi2 = 0;
        for (int u = 0; u < Un; ++u) {
            if (u == bi) continue;
            float v = scores[b * Un + u];
            if (v > best2) { best2 = v; bi2 = u; }
        }
        topi[b * 2] = bi;
        topi[b * 2 + 1] = bi2;
        ((int*)ws)[WS_TOPI + b * 2] = bi;
        ((int*)ws)[WS_TOPI + b * 2 + 1] = bi2;
        out[OUT_TOPI + b * 2] = (float)bi;
        out[OUT_TOPI + b * 2 + 1] = (float)bi2;
    }
    __syncthreads();
    if (tid == 0) {
        int cnt[Un];
        for (int u = 0; u < Un; ++u) cnt[u] = 0;
        for (int i = 0; i < Bn * 2; ++i) cnt[topi[i]]++;
        float lb = 0.f;
        for (int u = 0; u < Un; ++u) {
            float d = (float)cnt[u] * (1.f / 16.f) - 0.125f;
            lb += d * d;
        }
        out[OUT_LB] = lb * (1.f / Un);
    }
    float l2 = 0.f;
    l2 += sqrtf(block_sumsq(W1, HIDn * Cn, red));
    l2 += sqrtf(block_sumsq(b1, HIDn, red));
    l2 += sqrtf(block_sumsq(W2, HIDn * HIDn, red));
    l2 += sqrtf(block_sumsq(b2, HIDn, red));
    l2 += sqrtf(block_sumsq(W3, 64 * HIDn, red));
    l2 += sqrtf(block_sumsq(b3, 64, red));
    l2 += sqrtf(block_sumsq(W4, 64 * 64, red));
    l2 += sqrtf(block_sumsq(b4, 64, red));
    l2 += sqrtf(block_sumsq(Wu, Un * 64, red));
    l2 += sqrtf(block_sumsq(bu, Un, red));
    l2 += sqrtf(block_sumsq(Wc, Ln * 64, red));
    l2 += sqrtf(block_sumsq(bc, Ln, red));
    if (tid == 0) out[OUT_L2] = 0.01f * l2;
}

// -------- kernel 4: analytic gate + bias combo -----------------------------
// mean_pix(conv_u) computed in closed form: T(b,cin,tap) = S - Rexcl - Cexcl + corner
__global__ __launch_bounds__(256) void gate_kernel(const float* __restrict__ x,
                                                   const float* __restrict__ cb,
                                                   float* __restrict__ ws) {
    int tid = threadIdx.x;
    __shared__ float bsum[Un];
    __shared__ float gsum_sh[16];
    __shared__ float gate_sh[Bn * Un];
    if (tid < Un) {
        float s = 0.f;
        for (int c = 0; c < Cn; ++c) s += cb[tid * Cn + c];
        bsum[tid] = s;
    }
    const int* topi = (const int*)ws + WS_TOPI;
    int p = tid >> 4, j = tid & 15;  // 16 pairs x 16 threads
    int b = p >> 1, k = p & 1;
    int u = topi[b * 2 + k];
    float partial = 0.f;
    for (int cin = j; cin < Cn; cin += 16) {
        const float* st = ws + WS_STR + (b * Cn + cin) * 5;
        float S = st[0], R0 = st[1], R63 = st[2], C0 = st[3], C63 = st[4];
        const float* xp = x + ((size_t)b * Cn + cin) * HWn;
        float c00 = xp[0], c0r = xp[63], cb0 = xp[4032], cbr = xp[4095];
        const float* w9 = ws + WS_W9 + (u * Cn + cin) * 9;
        // ky=0 -> dy=-1 -> excluded input row 63; ky=2 -> excluded row 0
        float Rex[3] = {R63, 0.f, R0};
        float Cex[3] = {C63, 0.f, C0};
        float crn[3][3] = {{cbr, 0.f, cb0}, {0.f, 0.f, 0.f}, {c0r, 0.f, c00}};
        #pragma unroll
        for (int ky = 0; ky < 3; ++ky)
            #pragma unroll
            for (int kx = 0; kx < 3; ++kx) {
                float T = S - Rex[ky] - Cex[kx] + crn[ky][kx];
                partial = fmaf(w9[ky * 3 + kx], T, partial);
            }
    }
    #pragma unroll
    for (int off = 8; off > 0; off >>= 1) partial += __shfl_down(partial, off, 16);
    if (j == 0) gsum_sh[p] = partial;
    __syncthreads();
    if (tid < Bn) {
        int b2 = tid;
        int s0 = topi[b2 * 2], s1 = topi[b2 * 2 + 1];
        float lg[Un];
        for (int u2 = 0; u2 < Un; ++u2) lg[u2] = bsum[u2] * (1.0f / Cn);
        lg[s0] += gsum_sh[b2 * 2] * (1.0f / (Cn * HWn));
        lg[s1] += gsum_sh[b2 * 2 + 1] * (1.0f / (Cn * HWn));
        float m = -1e30f;
        for (int u2 = 0; u2 < Un; ++u2) m = fmaxf(m, lg[u2]);
        float den = 0.f, e[Un];
        for (int u2 = 0; u2 < Un; ++u2) { e[u2] = expf(lg[u2] - m); den += e[u2]; }
        float inv = 1.0f / den;
        for (int u2 = 0; u2 < Un; ++u2) gate_sh[b2 * Un + u2] = e[u2] * inv;
        ws[WS_GSEL + b2 * 2] = gate_sh[b2 * Un + s0];
        ws[WS_GSEL + b2 * 2 + 1] = gate_sh[b2 * Un + s1];
    }
    __syncthreads();
    for (int i = tid; i < Bn * Cn; i += 256) {
        int b2 = i >> 7, c = i & 127;
        float s = 0.f;
        for (int u2 = 0; u2 < Un; ++u2) s = fmaf(gate_sh[b2 * Un + u2], cb[u2 * Cn + c], s);
        ws[WS_BIASC + i] = s;
    }
}

// -------- kernel 5: fused conv (both units) -> gated final -----------------
// block = (b[8], g[16 groups of 8 couts], tile t[4] of 32x32); 256 threads
__global__ __launch_bounds__(256) void conv_fused_kernel(const float* __restrict__ x,
                                                         const float* __restrict__ cw,
                                                         const float* __restrict__ wsc,
                                                         float* __restrict__ out) {
    int bid = blockIdx.x;
    int b = bid >> 6;
    int g = (bid >> 2) & 15;
    int t = bid & 3;
    int oy = (t >> 1) * 32, ox = (t & 1) * 32;
    int tid = threadIdx.x;

    const int* topi = (const int*)wsc + WS_TOPI;
    int u0 = __builtin_amdgcn_readfirstlane(topi[b * 2]);
    int u1 = __builtin_amdgcn_readfirstlane(topi[b * 2 + 1]);
    float g0 = wsc[WS_GSEL + b * 2];
    float g1 = wsc[WS_GSEL + b * 2 + 1];

    __shared__ float xs[34 * 34];
    float acc[2][8][4];
    #pragma unroll
    for (int un = 0; un < 2; ++un)
        #pragma unroll
        for (int co = 0; co < 8; ++co)
            #pragma unroll
            for (int pp = 0; pp < 4; ++pp) acc[un][co][pp] = 0.f;

    const float* xb = x + (size_t)b * Cn * HWn;
    const float* wb0 = cw + ((size_t)u0 * Cn + g * 8) * (Cn * 9);
    const float* wb1 = cw + ((size_t)u1 * Cn + g * 8) * (Cn * 9);

    for (int cin = 0; cin < Cn; ++cin) {
        __syncthreads();
        const float* xp = xb + (size_t)cin * HWn;
        for (int i = tid; i < 34 * 34; i += 256) {
            int ly = i / 34, lx = i - ly * 34;
            int gy = oy + ly - 1, gx = ox + lx - 1;
            float v = 0.f;
            if ((unsigned)gy < 64u && (unsigned)gx < 64u) v = xp[(gy << 6) + gx];
            xs[i] = v;
        }
        __syncthreads();

        float xv[4][9];
        #pragma unroll
        for (int pp = 0; pp < 4; ++pp) {
            int li = tid + pp * 256;
            int lr = li >> 5, lc = li & 31;
            #pragma unroll
            for (int ky = 0; ky < 3; ++ky)
                #pragma unroll
                for (int kx = 0; kx < 3; ++kx)
                    xv[pp][ky * 3 + kx] = xs[(lr + ky) * 34 + lc + kx];
        }
        const float* w0c = wb0 + cin * 9;
        const float* w1c = wb1 + cin * 9;
        #pragma unroll
        for (int co = 0; co < 8; ++co) {
            const float* wA = w0c + co * (Cn * 9);
            const float* wB = w1c + co * (Cn * 9);
            #pragma unroll
            for (int tap = 0; tap < 9; ++tap) {
                float wa = wA[tap], wb_ = wB[tap];
                #pragma unroll
                for (int pp = 0; pp < 4; ++pp) {
                    acc[0][co][pp] = fmaf(wa, xv[pp][tap], acc[0][co][pp]);
                    acc[1][co][pp] = fmaf(wb_, xv[pp][tap], acc[1][co][pp]);
                }
            }
        }
    }

    #pragma unroll
    for (int co = 0; co < 8; ++co) {
        int c = g * 8 + co;
        float bias = wsc[WS_BIASC + b * Cn + c];
        float* dp = out + OUT_FINAL + ((size_t)b * Cn + c) * HWn;
        #pragma unroll
        for (int pp = 0; pp < 4; ++pp) {
            int li = tid + pp * 256;
            int lr = li >> 5, lc = li & 31;
            dp[((oy + lr) << 6) + (ox + lc)] =
                fmaf(g0, acc[0][co][pp], fmaf(g1, acc[1][co][pp], bias));
        }
    }
}

extern "C" void kernel_launch(void* const* d_in, const int* in_sizes, int n_in,
                              void* d_out, int out_size, void* d_ws, size_t ws_size,
                              hipStream_t stream) {
    const float* x  = (const float*)d_in[0];
    const float* W1 = (const float*)d_in[1];
    const float* b1 = (const float*)d_in[2];
    const float* W2 = (const float*)d_in[3];
    const float* b2 = (const float*)d_in[4];
    const float* W3 = (const float*)d_in[5];
    const float* b3 = (const float*)d_in[6];
    const float* W4 = (const float*)d_in[7];
    const float* b4 = (const float*)d_in[8];
    const float* Wu = (const float*)d_in[9];
    const float* bu = (const float*)d_in[10];
    const float* Wc = (const float*)d_in[11];
    const float* bc = (const float*)d_in[12];
    const float* cw = (const float*)d_in[13];
    const float* cb = (const float*)d_in[14];
    float* out = (float*)d_out;
    float* ws  = (float*)d_ws;

    pool_strips_kernel<<<Bn * Cn, 256, 0, stream>>>(x, ws);
    w9sum_kernel<<<36, 256, 0, stream>>>(cw, ws);
    router_kernel<<<1, 256, 0, stream>>>(W1, b1, W2, b2, W3, b3, W4, b4,
                                         Wu, bu, Wc, bc, ws, out);
    gate_kernel<<<1, 256, 0, stream>>>(x, cb, ws);
    conv_fused_kernel<<<8 * 16 * 4, 256, 0, stream>>>(x, cw, ws, out);
}

// Round 3
// 371.568 us; speedup vs baseline: 1.5306x; 1.5306x over previous
//
#include <hip/hip_runtime.h>
#include <math.h>

// Problem constants
#define Bn   8
#define Cn   128
#define Hn   64
#define Wn   64
#define HWn  4096
#define Un   8
#define Ln   10
#define HIDn 128

// d_out layout (float offsets): final, cls_logits, l2_reg, top_i, lb_loss
#define OUT_FINAL 0
#define OUT_CLS   4194304
#define OUT_L2    4194384
#define OUT_TOPI  4194385
#define OUT_LB    4194401

// ws layout (float offsets)
#define WS_POOLED 0                      // [1024]
#define WS_STR    1024                   // [1024*5]  S,R0,R63,C0,C63 per (b,cin)
#define WS_W9     6144                   // [8*128*9] sum_cout w[u][cout][cin][tap]
#define WS_TOPI   15360                  // int[16]
#define WS_GSEL   15376                  // [16]
#define WS_BIASC  15392                  // [1024]   sum_u gate[b][u]*conv_b[u*C+c]
#define WS_XT     16416                  // bf16 xt[8][64][64][128] = 2097152 floats
#define WS_WCOMB  2113568                // bf16 wcomb[8][9][128][128] = 589824 floats

#define NOISE_PARTITIONABLE 1

typedef __attribute__((ext_vector_type(8))) short bf16x8;
typedef __attribute__((ext_vector_type(4))) float f32x4;

__device__ __forceinline__ unsigned short f2bf(float f) {
    unsigned u = __float_as_uint(f);
    unsigned r = (u + 0x7fffu + ((u >> 16) & 1u)) >> 16;
    return (unsigned short)r;
}

// ---------------- jax threefry2x32 noise (key=42, shape (8,8)) --------------
__device__ __forceinline__ unsigned rotl32(unsigned x, int d) {
    return (x << d) | (x >> (32 - d));
}

__device__ __forceinline__ void threefry2x32(unsigned k1, unsigned k2,
                                             unsigned c0, unsigned c1,
                                             unsigned* o0, unsigned* o1) {
    unsigned ks0 = k1, ks1 = k2, ks2 = k1 ^ k2 ^ 0x1BD11BDAu;
    unsigned ksa[3] = {ks0, ks1, ks2};
    const int rot[2][4] = {{13, 15, 26, 6}, {17, 29, 16, 24}};
    unsigned x0 = c0 + ks0, x1 = c1 + ks1;
    #pragma unroll
    for (int s = 0; s < 5; ++s) {
        #pragma unroll
        for (int q = 0; q < 4; ++q) {
            x0 += x1;
            x1 = rotl32(x1, rot[s & 1][q]);
            x1 ^= x0;
        }
        x0 += ksa[(s + 1) % 3];
        x1 += ksa[(s + 2) % 3] + (unsigned)(s + 1);
    }
    *o0 = x0;
    *o1 = x1;
}

__device__ float jax_noise_elem(int i) {
    unsigned o0, o1, bits;
#if NOISE_PARTITIONABLE
    threefry2x32(0u, 42u, 0u, (unsigned)i, &o0, &o1);
    bits = o0 ^ o1;
#else
    {
        int second = (i >= 32);
        unsigned j = (unsigned)(second ? i - 32 : i);
        threefry2x32(0u, 42u, j, j + 32u, &o0, &o1);
        bits = second ? o1 : o0;
    }
#endif
    unsigned fb = (bits >> 9) | 0x3f800000u;
    float f = __uint_as_float(fb) - 1.0f;
    const float lo = __uint_as_float(0xBF7FFFFFu);
    float u = f * (1.0f - lo) + lo;
    u = fmaxf(lo, u);
    float w = -log1pf(-u * u);
    float p;
    if (w < 5.0f) {
        w = w - 2.5f;
        p = 2.81022636e-08f;
        p = fmaf(p, w, 3.43273939e-07f);
        p = fmaf(p, w, -3.5233877e-06f);
        p = fmaf(p, w, -4.39150654e-06f);
        p = fmaf(p, w, 0.00021858087f);
        p = fmaf(p, w, -0.00125372503f);
        p = fmaf(p, w, -0.00417768164f);
        p = fmaf(p, w, 0.246640727f);
        p = fmaf(p, w, 1.50140941f);
    } else {
        w = sqrtf(w) - 3.0f;
        p = -0.000200214257f;
        p = fmaf(p, w, 0.000100950558f);
        p = fmaf(p, w, 0.00134934322f);
        p = fmaf(p, w, -0.00367342844f);
        p = fmaf(p, w, 0.00573950773f);
        p = fmaf(p, w, -0.0076224613f);
        p = fmaf(p, w, 0.00943887047f);
        p = fmaf(p, w, 1.00167406f);
        p = fmaf(p, w, 2.83297682f);
    }
    float n = 1.41421356237309515f * (p * u);
    return n * 0.01f;
}

// -------- kernel 1: fused xprep(512) + pool/strips(1024) + w9sum(8) --------
__global__ __launch_bounds__(256) void prep_kernel(const float* __restrict__ x,
                                                   const float* __restrict__ cw,
                                                   float* __restrict__ ws) {
    __shared__ float smem[8256];
    int bid = blockIdx.x;
    int tid = threadIdx.x;

    if (bid < 512) {
        // ---- x transpose to channel-last bf16: xt[b][y][x][cin] ----
        int b = bid >> 6, y = bid & 63;
        #pragma unroll
        for (int k = 0; k < 32; ++k) {
            int cin = (tid >> 6) + (k << 2);
            int xcol = tid & 63;
            smem[xcol * 129 + cin] =
                x[(((size_t)b * 128 + cin) << 12) + (y << 6) + xcol];
        }
        __syncthreads();
        unsigned short* xtp = (unsigned short*)(ws + WS_XT);
        #pragma unroll
        for (int i = 0; i < 4; ++i) {
            int op = tid + (i << 8);          // 0..1023
            int px = op >> 4, part = op & 15;
            const float* src = smem + px * 129 + part * 8;
            uint4 u;
            u.x = (unsigned)f2bf(src[0]) | ((unsigned)f2bf(src[1]) << 16);
            u.y = (unsigned)f2bf(src[2]) | ((unsigned)f2bf(src[3]) << 16);
            u.z = (unsigned)f2bf(src[4]) | ((unsigned)f2bf(src[5]) << 16);
            u.w = (unsigned)f2bf(src[6]) | ((unsigned)f2bf(src[7]) << 16);
            *(uint4*)(xtp + (((((size_t)b * 64 + y) * 64 + px) << 7) + (part << 3))) = u;
        }
    } else if (bid < 1536) {
        // ---- avg pool + border strips per (b,cin) ----
        int bc = bid - 512;
        const float4* p4 = (const float4*)(x + (size_t)bc * HWn);
        float S = 0.f, R0 = 0.f, R63 = 0.f, C0 = 0.f, C63 = 0.f;
        #pragma unroll
        for (int it = 0; it < 4; ++it) {
            int i = tid + it * 256;
            float4 v = p4[i];
            float s4 = v.x + v.y + v.z + v.w;
            S += s4;
            if (i < 16) R0 += s4;
            if (i >= 1008) R63 += s4;
            if ((i & 15) == 0) C0 += v.x;
            if ((i & 15) == 15) C63 += v.w;
        }
        float* red = smem;
        float vals[5] = {S, R0, R63, C0, C63};
        float outv[5];
        for (int s = 0; s < 5; ++s) {
            __syncthreads();
            red[tid] = vals[s];
            __syncthreads();
            for (int off = 128; off > 0; off >>= 1) {
                if (tid < off) red[tid] += red[tid + off];
                __syncthreads();
            }
            outv[s] = red[0];
        }
        if (tid == 0) {
            ws[WS_POOLED + bc] = outv[0] * (1.0f / HWn);
            float* st = ws + WS_STR + bc * 5;
            st[0] = outv[0]; st[1] = outv[1]; st[2] = outv[2];
            st[3] = outv[3]; st[4] = outv[4];
        }
    } else {
        // ---- W9sum[u][cin][tap] = sum_cout conv_w (coalesced) ----
        int u = bid - 1536;
        float a[5] = {0.f, 0.f, 0.f, 0.f, 0.f};
        const float* base = cw + (size_t)u * 128 * 1152;
        for (int cout = 0; cout < 128; ++cout) {
            const float* row = base + (size_t)cout * 1152;
            #pragma unroll
            for (int j = 0; j < 5; ++j) {
                int e = tid + j * 256;
                if (e < 1152) a[j] += row[e];
            }
        }
        #pragma unroll
        for (int j = 0; j < 5; ++j) {
            int e = tid + j * 256;
            if (e < 1152) ws[WS_W9 + u * 1152 + e] = a[j];
        }
    }
}

// -------- block sum-of-squares helper --------------------------------------
__device__ float block_sumsq(const float* __restrict__ p, int n, float* red) {
    int tid = threadIdx.x;
    float s = 0.f;
    for (int i = tid; i < n; i += 256) { float v = p[i]; s = fmaf(v, v, s); }
    __syncthreads();
    red[tid] = s;
    __syncthreads();
    for (int off = 128; off > 0; off >>= 1) {
        if (tid < off) red[tid] += red[tid + off];
        __syncthreads();
    }
    return red[0];
}

// -------- kernel 2: router MLP + noise + topk + l2 + lb + analytic gate ----
__global__ __launch_bounds__(256) void router_gate_kernel(
    const float* __restrict__ x,
    const float* __restrict__ W1, const float* __restrict__ b1,
    const float* __restrict__ W2, const float* __restrict__ b2,
    const float* __restrict__ W3, const float* __restrict__ b3,
    const float* __restrict__ W4, const float* __restrict__ b4,
    const float* __restrict__ Wu, const float* __restrict__ bu,
    const float* __restrict__ Wc, const float* __restrict__ bc,
    const float* __restrict__ cb,
    float* __restrict__ ws, float* __restrict__ out) {
    __shared__ float pooled[Bn * Cn];
    __shared__ float h1[Bn * HIDn];
    __shared__ float h2[Bn * HIDn];
    __shared__ float h3[Bn * 64];
    __shared__ float feat[Bn * 64];
    __shared__ float scores[Bn * Un];
    __shared__ float noise[64];
    __shared__ float red[256];
    __shared__ int topi[Bn * 2];
    __shared__ float bsum[Un];
    __shared__ float gsum_sh[16];
    __shared__ float gate_sh[Bn * Un];
    int tid = threadIdx.x;

    for (int i = tid; i < Bn * Cn; i += 256) pooled[i] = ws[WS_POOLED + i];
    __syncthreads();

    for (int i = tid; i < Bn * HIDn; i += 256) {
        int b = i / HIDn, j = i % HIDn;
        float s = b1[j];
        const float* wr = W1 + j * Cn;
        for (int k = 0; k < Cn; ++k) s = fmaf(pooled[b * Cn + k], wr[k], s);
        h1[i] = fmaxf(s, 0.f);
    }
    __syncthreads();
    for (int i = tid; i < Bn * HIDn; i += 256) {
        int b = i / HIDn, j = i % HIDn;
        float s = b2[j];
        const float* wr = W2 + j * HIDn;
        for (int k = 0; k < HIDn; ++k) s = fmaf(h1[b * HIDn + k], wr[k], s);
        h2[i] = fmaxf(s, 0.f);
    }
    __syncthreads();
    for (int i = tid; i < Bn * 64; i += 256) {
        int b = i / 64, j = i % 64;
        float s = b3[j];
        const float* wr = W3 + j * HIDn;
        for (int k = 0; k < HIDn; ++k) s = fmaf(h2[b * HIDn + k], wr[k], s);
        h3[i] = fmaxf(s, 0.f);
    }
    __syncthreads();
    for (int i = tid; i < Bn * 64; i += 256) {
        int b = i / 64, j = i % 64;
        float s = b4[j];
        const float* wr = W4 + j * 64;
        for (int k = 0; k < 64; ++k) s = fmaf(h3[b * 64 + k], wr[k], s);
        feat[i] = s;
    }
    __syncthreads();
    if (tid < 64) noise[tid] = jax_noise_elem(tid);
    if (tid < Bn * Un) {
        int b = tid / Un, u = tid % Un;
        float s = bu[u];
        const float* wr = Wu + u * 64;
        for (int k = 0; k < 64; ++k) s = fmaf(feat[b * 64 + k], wr[k], s);
        scores[tid] = s;
    }
    for (int i = tid; i < Bn * Ln; i += 256) {
        int b = i / Ln, j = i % Ln;
        float s = bc[j];
        const float* wr = Wc + j * 64;
        for (int k = 0; k < 64; ++k) s = fmaf(feat[b * 64 + k], wr[k], s);
        out[OUT_CLS + i] = s;
    }
    __syncthreads();
    if (tid < Bn * Un) scores[tid] += noise[tid];
    __syncthreads();
    if (tid < Bn) {
        int b = tid;
        float best = -1e30f; int bi = 0;
        for (int u = 0; u < Un; ++u) {
            float v = scores[b * Un + u];
            if (v > best) { best = v; bi = u; }
        }
        float best2 = -1e30f; int bi2 = 0;
        for (int u = 0; u < Un; ++u) {
            if (u == bi) continue;
            float v = scores[b * Un + u];
            if (v > best2) { best2 = v; bi2 = u; }
        }
        topi[b * 2] = bi;
        topi[b * 2 + 1] = bi2;
        ((int*)ws)[WS_TOPI + b * 2] = bi;
        ((int*)ws)[WS_TOPI + b * 2 + 1] = bi2;
        out[OUT_TOPI + b * 2] = (float)bi;
        out[OUT_TOPI + b * 2 + 1] = (float)bi2;
    }
    __syncthreads();
    if (tid == 0) {
        int cnt[Un];
        for (int u = 0; u < Un; ++u) cnt[u] = 0;
        for (int i = 0; i < Bn * 2; ++i) cnt[topi[i]]++;
        float lb = 0.f;
        for (int u = 0; u < Un; ++u) {
            float d = (float)cnt[u] * (1.f / 16.f) - 0.125f;
            lb += d * d;
        }
        out[OUT_LB] = lb * (1.f / Un);
    }
    float l2 = 0.f;
    l2 += sqrtf(block_sumsq(W1, HIDn * Cn, red));
    l2 += sqrtf(block_sumsq(b1, HIDn, red));
    l2 += sqrtf(block_sumsq(W2, HIDn * HIDn, red));
    l2 += sqrtf(block_sumsq(b2, HIDn, red));
    l2 += sqrtf(block_sumsq(W3, 64 * HIDn, red));
    l2 += sqrtf(block_sumsq(b3, 64, red));
    l2 += sqrtf(block_sumsq(W4, 64 * 64, red));
    l2 += sqrtf(block_sumsq(b4, 64, red));
    l2 += sqrtf(block_sumsq(Wu, Un * 64, red));
    l2 += sqrtf(block_sumsq(bu, Un, red));
    l2 += sqrtf(block_sumsq(Wc, Ln * 64, red));
    l2 += sqrtf(block_sumsq(bc, Ln, red));
    if (tid == 0) out[OUT_L2] = 0.01f * l2;
    __syncthreads();

    // ---- analytic gate from border strips ----
    if (tid < Un) {
        float s = 0.f;
        for (int c = 0; c < Cn; ++c) s += cb[tid * Cn + c];
        bsum[tid] = s;
    }
    __syncthreads();
    {
        int p = tid >> 4, j = tid & 15;
        int b = p >> 1, k = p & 1;
        int u = topi[b * 2 + k];
        float partial = 0.f;
        for (int cin = j; cin < Cn; cin += 16) {
            const float* st = ws + WS_STR + (b * Cn + cin) * 5;
            float S = st[0], R0 = st[1], R63 = st[2], C0 = st[3], C63 = st[4];
            const float* xp = x + ((size_t)b * Cn + cin) * HWn;
            float c00 = xp[0], c0r = xp[63], cb0 = xp[4032], cbr = xp[4095];
            const float* w9 = ws + WS_W9 + (u * Cn + cin) * 9;
            float Rex[3] = {R63, 0.f, R0};
            float Cex[3] = {C63, 0.f, C0};
            float crn[3][3] = {{cbr, 0.f, cb0}, {0.f, 0.f, 0.f}, {c0r, 0.f, c00}};
            #pragma unroll
            for (int ky = 0; ky < 3; ++ky)
                #pragma unroll
                for (int kx = 0; kx < 3; ++kx) {
                    float T = S - Rex[ky] - Cex[kx] + crn[ky][kx];
                    partial = fmaf(w9[ky * 3 + kx], T, partial);
                }
        }
        #pragma unroll
        for (int off = 8; off > 0; off >>= 1)
            partial += __shfl_down(partial, off, 16);
        if (j == 0) gsum_sh[p] = partial;
    }
    __syncthreads();
    if (tid < Bn) {
        int b2 = tid;
        int s0 = topi[b2 * 2], s1 = topi[b2 * 2 + 1];
        float lg[Un];
        for (int u2 = 0; u2 < Un; ++u2) lg[u2] = bsum[u2] * (1.0f / Cn);
        lg[s0] += gsum_sh[b2 * 2] * (1.0f / (Cn * HWn));
        lg[s1] += gsum_sh[b2 * 2 + 1] * (1.0f / (Cn * HWn));
        float m = -1e30f;
        for (int u2 = 0; u2 < Un; ++u2) m = fmaxf(m, lg[u2]);
        float den = 0.f, e[Un];
        for (int u2 = 0; u2 < Un; ++u2) { e[u2] = expf(lg[u2] - m); den += e[u2]; }
        float inv = 1.0f / den;
        for (int u2 = 0; u2 < Un; ++u2) gate_sh[b2 * Un + u2] = e[u2] * inv;
        ws[WS_GSEL + b2 * 2] = gate_sh[b2 * Un + s0];
        ws[WS_GSEL + b2 * 2 + 1] = gate_sh[b2 * Un + s1];
    }
    __syncthreads();
    for (int i = tid; i < Bn * Cn; i += 256) {
        int b2 = i >> 7, c = i & 127;
        float s = 0.f;
        for (int u2 = 0; u2 < Un; ++u2)
            s = fmaf(gate_sh[b2 * Un + u2], cb[u2 * Cn + c], s);
        ws[WS_BIASC + i] = s;
    }
}

// -------- kernel 3: gate-combined weights -> bf16 [b][tap][cout][cin] ------
__global__ __launch_bounds__(256) void wprep_kernel(const float* __restrict__ cw,
                                                    float* __restrict__ ws) {
    int bid = blockIdx.x;        // b*9 + tap
    int b = bid / 9, tap = bid - b * 9;
    const int* topi = (const int*)ws + WS_TOPI;
    int u0 = topi[b * 2], u1 = topi[b * 2 + 1];
    float g0 = ws[WS_GSEL + b * 2], g1 = ws[WS_GSEL + b * 2 + 1];
    unsigned short* wc = (unsigned short*)(ws + WS_WCOMB);
    for (int i = 0; i < 64; ++i) {
        int e = threadIdx.x + (i << 8);      // 0..16383
        int cout = e >> 7, cin = e & 127;
        size_t i0 = (((size_t)u0 * 128 + cout) * 128 + cin) * 9 + tap;
        size_t i1 = (((size_t)u1 * 128 + cout) * 128 + cin) * 9 + tap;
        float v = g0 * cw[i0] + g1 * cw[i1];
        wc[((size_t)bid << 14) + e] = f2bf(v);
    }
}

// -------- kernel 4: MFMA implicit-GEMM conv + gated combine ----------------
// block = (b[8], row y[64]); 128 threads = 2 waves (cout halves 0-63 / 64-127)
// wave tile: M=64 couts x N=64 pix; K = 9 taps x 128 cin via 16x16x32 bf16 MFMA
__global__ __launch_bounds__(128) void conv_mfma_kernel(
    const float* __restrict__ wsf, float* __restrict__ out) {
    const unsigned short* __restrict__ xt = (const unsigned short*)(wsf + WS_XT);
    const unsigned short* __restrict__ wc = (const unsigned short*)(wsf + WS_WCOMB);

    int bid = blockIdx.x;
    int b = bid >> 6, y = bid & 63;
    int tid = threadIdx.x;
    int wave = tid >> 6, lane = tid & 63;
    int quad = lane >> 4, l15 = lane & 15;
    int m0 = wave << 6;

    // halo 3 rows x 66 cols, 32 cin (one chunk), 80 B per pixel (8 B pad)
    __shared__ __align__(16) unsigned short xs[198 * 40];

    f32x4 acc[4][4];
    #pragma unroll
    for (int mt = 0; mt < 4; ++mt)
        #pragma unroll
        for (int nt = 0; nt < 4; ++nt)
            acc[mt][nt] = (f32x4){0.f, 0.f, 0.f, 0.f};

    int ldsrd = l15 * 80 + quad * 16;  // per-lane LDS read base (bytes)

    for (int chunk = 0; chunk < 4; ++chunk) {
        if (chunk) __syncthreads();
        // stage 198 pixels x 64 B (this chunk's 32 cin) = 792 x 16 B ops
        #pragma unroll
        for (int i = 0; i < 7; ++i) {
            int o = tid + i * 128;
            if (o < 792) {
                int px = o >> 2, part = o & 3;
                int r3 = px / 66;
                int col = px - r3 * 66;
                int ry = y + r3 - 1;
                int gx = col - 1;
                uint4 v = {0u, 0u, 0u, 0u};
                if ((unsigned)ry < 64u && (unsigned)gx < 64u) {
                    v = *(const uint4*)(xt +
                        ((((size_t)b * 64 + ry) * 64 + gx) << 7) +
                        (chunk << 5) + (part << 3));
                }
                *(uint4*)((char*)xs + px * 80 + part * 16) = v;
            }
        }
        __syncthreads();
        #pragma unroll
        for (int tap = 0; tap < 9; ++tap) {
            const int dy = tap / 3, dx = tap % 3;
            bf16x8 af[4];
            #pragma unroll
            for (int mt = 0; mt < 4; ++mt) {
                int cout = m0 + mt * 16 + l15;
                af[mt] = *(const bf16x8*)(wc +
                    ((((size_t)b * 9 + tap) << 7) + cout) * 128 +
                    (chunk << 5) + (quad << 3));
            }
            bf16x8 bfr[4];
            #pragma unroll
            for (int nt = 0; nt < 4; ++nt) {
                int off = (dy * 66 + dx + nt * 16) * 80;
                bfr[nt] = *(const bf16x8*)((char*)xs + ldsrd + off);
            }
            #pragma unroll
            for (int mt = 0; mt < 4; ++mt)
                #pragma unroll
                for (int nt = 0; nt < 4; ++nt)
                    acc[mt][nt] = __builtin_amdgcn_mfma_f32_16x16x32_bf16(
                        af[mt], bfr[nt], acc[mt][nt], 0, 0, 0);
        }
    }

    // epilogue: D[m=quad*4+r][n=l15]; add combined bias; store
    #pragma unroll
    for (int mt = 0; mt < 4; ++mt) {
        #pragma unroll
        for (int r = 0; r < 4; ++r) {
            int c = m0 + mt * 16 + (quad << 2) + r;
            float bias = wsf[WS_BIASC + (b << 7) + c];
            size_t rowb = (((size_t)b * 128 + c) << 12) + (y << 6);
            #pragma unroll
            for (int nt = 0; nt < 4; ++nt)
                out[rowb + nt * 16 + l15] = acc[mt][nt][r] + bias;
        }
    }
}

extern "C" void kernel_launch(void* const* d_in, const int* in_sizes, int n_in,
                              void* d_out, int out_size, void* d_ws, size_t ws_size,
                              hipStream_t stream) {
    const float* x  = (const float*)d_in[0];
    const float* W1 = (const float*)d_in[1];
    const float* b1 = (const float*)d_in[2];
    const float* W2 = (const float*)d_in[3];
    const float* b2 = (const float*)d_in[4];
    const float* W3 = (const float*)d_in[5];
    const float* b3 = (const float*)d_in[6];
    const float* W4 = (const float*)d_in[7];
    const float* b4 = (const float*)d_in[8];
    const float* Wu = (const float*)d_in[9];
    const float* bu = (const float*)d_in[10];
    const float* Wc = (const float*)d_in[11];
    const float* bc = (const float*)d_in[12];
    const float* cw = (const float*)d_in[13];
    const float* cb = (const float*)d_in[14];
    float* out = (float*)d_out;
    float* ws  = (float*)d_ws;

    prep_kernel<<<1544, 256, 0, stream>>>(x, cw, ws);
    router_gate_kernel<<<1, 256, 0, stream>>>(x, W1, b1, W2, b2, W3, b3, W4, b4,
                                              Wu, bu, Wc, bc, cb, ws, out);
    wprep_kernel<<<72, 256, 0, stream>>>(cw, ws);
    conv_mfma_kernel<<<512, 128, 0, stream>>>(ws, out);
}

// Round 4
// 218.527 us; speedup vs baseline: 2.6026x; 1.7003x over previous
//
#include <hip/hip_runtime.h>
#include <math.h>

// Problem constants
#define Bn   8
#define Cn   128
#define Hn   64
#define Wn   64
#define HWn  4096
#define Un   8
#define Ln   10
#define HIDn 128

// d_out layout (float offsets): final, cls_logits, l2_reg, top_i, lb_loss
#define OUT_FINAL 0
#define OUT_CLS   4194304
#define OUT_L2    4194384
#define OUT_TOPI  4194385
#define OUT_LB    4194401

// ws layout (float offsets)
#define WS_POOLED 0                      // [1024]
#define WS_STR    1024                   // [1024*5]  S,R0,R63,C0,C63 per (b,cin)
#define WS_W9     6144                   // [8*128*9] reduced sum_cout w[u][cout][cin][tap]
#define WS_TOPI   15360                  // int[16]
#define WS_GSEL   15376                  // [16]
#define WS_BIASC  15392                  // [1024]   sum_u gate[b][u]*conv_b[u*C+c]
#define WS_W9P    16416                  // [64][1152] w9 partials per (u,g)
#define WS_XT     90144                  // bf16 xt[8][64][64][128] = 2097152 floats
#define WS_WCOMB  2187296                // bf16 wcomb[8][128][9][128] = 589824 floats

#define NOISE_PARTITIONABLE 1

typedef __attribute__((ext_vector_type(8))) short bf16x8;
typedef __attribute__((ext_vector_type(4))) float f32x4;

__device__ __forceinline__ unsigned short f2bf(float f) {
    unsigned u = __float_as_uint(f);
    unsigned r = (u + 0x7fffu + ((u >> 16) & 1u)) >> 16;
    return (unsigned short)r;
}

// ---------------- jax threefry2x32 noise (key=42, shape (8,8)) --------------
__device__ __forceinline__ unsigned rotl32(unsigned x, int d) {
    return (x << d) | (x >> (32 - d));
}

__device__ __forceinline__ void threefry2x32(unsigned k1, unsigned k2,
                                             unsigned c0, unsigned c1,
                                             unsigned* o0, unsigned* o1) {
    unsigned ks0 = k1, ks1 = k2, ks2 = k1 ^ k2 ^ 0x1BD11BDAu;
    unsigned ksa[3] = {ks0, ks1, ks2};
    const int rot[2][4] = {{13, 15, 26, 6}, {17, 29, 16, 24}};
    unsigned x0 = c0 + ks0, x1 = c1 + ks1;
    #pragma unroll
    for (int s = 0; s < 5; ++s) {
        #pragma unroll
        for (int q = 0; q < 4; ++q) {
            x0 += x1;
            x1 = rotl32(x1, rot[s & 1][q]);
            x1 ^= x0;
        }
        x0 += ksa[(s + 1) % 3];
        x1 += ksa[(s + 2) % 3] + (unsigned)(s + 1);
    }
    *o0 = x0;
    *o1 = x1;
}

__device__ float jax_noise_elem(int i) {
    unsigned o0, o1, bits;
#if NOISE_PARTITIONABLE
    threefry2x32(0u, 42u, 0u, (unsigned)i, &o0, &o1);
    bits = o0 ^ o1;
#else
    {
        int second = (i >= 32);
        unsigned j = (unsigned)(second ? i - 32 : i);
        threefry2x32(0u, 42u, j, j + 32u, &o0, &o1);
        bits = second ? o1 : o0;
    }
#endif
    unsigned fb = (bits >> 9) | 0x3f800000u;
    float f = __uint_as_float(fb) - 1.0f;
    const float lo = __uint_as_float(0xBF7FFFFFu);
    float u = f * (1.0f - lo) + lo;
    u = fmaxf(lo, u);
    float w = -log1pf(-u * u);
    float p;
    if (w < 5.0f) {
        w = w - 2.5f;
        p = 2.81022636e-08f;
        p = fmaf(p, w, 3.43273939e-07f);
        p = fmaf(p, w, -3.5233877e-06f);
        p = fmaf(p, w, -4.39150654e-06f);
        p = fmaf(p, w, 0.00021858087f);
        p = fmaf(p, w, -0.00125372503f);
        p = fmaf(p, w, -0.00417768164f);
        p = fmaf(p, w, 0.246640727f);
        p = fmaf(p, w, 1.50140941f);
    } else {
        w = sqrtf(w) - 3.0f;
        p = -0.000200214257f;
        p = fmaf(p, w, 0.000100950558f);
        p = fmaf(p, w, 0.00134934322f);
        p = fmaf(p, w, -0.00367342844f);
        p = fmaf(p, w, 0.00573950773f);
        p = fmaf(p, w, -0.0076224613f);
        p = fmaf(p, w, 0.00943887047f);
        p = fmaf(p, w, 1.00167406f);
        p = fmaf(p, w, 2.83297682f);
    }
    float n = 1.41421356237309515f * (p * u);
    return n * 0.01f;
}

// -------- kernel 1: fused xprep(512) + pool/strips(1024) + w9 partials(64) --
__global__ __launch_bounds__(256) void prep_kernel(const float* __restrict__ x,
                                                   const float* __restrict__ cw,
                                                   float* __restrict__ ws) {
    __shared__ float smem[8256];
    int bid = blockIdx.x;
    int tid = threadIdx.x;

    if (bid < 512) {
        // ---- x transpose to channel-last bf16: xt[b][y][x][cin] ----
        int b = bid >> 6, y = bid & 63;
        #pragma unroll
        for (int k = 0; k < 32; ++k) {
            int cin = (tid >> 6) + (k << 2);
            int xcol = tid & 63;
            smem[xcol * 129 + cin] =
                x[(((size_t)b * 128 + cin) << 12) + (y << 6) + xcol];
        }
        __syncthreads();
        unsigned short* xtp = (unsigned short*)(ws + WS_XT);
        #pragma unroll
        for (int i = 0; i < 4; ++i) {
            int op = tid + (i << 8);          // 0..1023
            int px = op >> 4, part = op & 15;
            const float* src = smem + px * 129 + part * 8;
            uint4 u;
            u.x = (unsigned)f2bf(src[0]) | ((unsigned)f2bf(src[1]) << 16);
            u.y = (unsigned)f2bf(src[2]) | ((unsigned)f2bf(src[3]) << 16);
            u.z = (unsigned)f2bf(src[4]) | ((unsigned)f2bf(src[5]) << 16);
            u.w = (unsigned)f2bf(src[6]) | ((unsigned)f2bf(src[7]) << 16);
            *(uint4*)(xtp + (((((size_t)b * 64 + y) * 64 + px) << 7) + (part << 3))) = u;
        }
    } else if (bid < 1536) {
        // ---- avg pool + border strips per (b,cin) ----
        int bc = bid - 512;
        const float4* p4 = (const float4*)(x + (size_t)bc * HWn);
        float S = 0.f, R0 = 0.f, R63 = 0.f, C0 = 0.f, C63 = 0.f;
        #pragma unroll
        for (int it = 0; it < 4; ++it) {
            int i = tid + it * 256;
            float4 v = p4[i];
            float s4 = v.x + v.y + v.z + v.w;
            S += s4;
            if (i < 16) R0 += s4;
            if (i >= 1008) R63 += s4;
            if ((i & 15) == 0) C0 += v.x;
            if ((i & 15) == 15) C63 += v.w;
        }
        float* red = smem;
        float vals[5] = {S, R0, R63, C0, C63};
        float outv[5];
        for (int s = 0; s < 5; ++s) {
            __syncthreads();
            red[tid] = vals[s];
            __syncthreads();
            for (int off = 128; off > 0; off >>= 1) {
                if (tid < off) red[tid] += red[tid + off];
                __syncthreads();
            }
            outv[s] = red[0];
        }
        if (tid == 0) {
            ws[WS_POOLED + bc] = outv[0] * (1.0f / HWn);
            float* st = ws + WS_STR + bc * 5;
            st[0] = outv[0]; st[1] = outv[1]; st[2] = outv[2];
            st[3] = outv[3]; st[4] = outv[4];
        }
    } else {
        // ---- w9 partials: block (u,g) sums couts g*16..g*16+15 ----
        // unguarded unrolled loads -> deep pipelining (R3's guarded 8-block
        // version serialized ~640 HBM round-trips = 240us)
        int idx = bid - 1536;            // 0..63
        int u = idx >> 3, g = idx & 7;
        const float* base = cw + (size_t)u * 147456 + (size_t)g * 18432;
        float a0 = 0.f, a1 = 0.f, a2 = 0.f, a3 = 0.f, a4 = 0.f;
        #pragma unroll
        for (int cout = 0; cout < 16; ++cout) {
            const float* row = base + (size_t)cout * 1152;
            a0 += row[tid];
            a1 += row[tid + 256];
            a2 += row[tid + 512];
            a3 += row[tid + 768];
            if (tid < 128) a4 += row[tid + 1024];
        }
        float* dst = ws + WS_W9P + (size_t)idx * 1152;
        dst[tid] = a0;
        dst[tid + 256] = a1;
        dst[tid + 512] = a2;
        dst[tid + 768] = a3;
        if (tid < 128) dst[tid + 1024] = a4;
    }
}

// -------- block sum-of-squares helper --------------------------------------
__device__ float block_sumsq(const float* __restrict__ p, int n, float* red) {
    int tid = threadIdx.x;
    float s = 0.f;
    for (int i = tid; i < n; i += 256) { float v = p[i]; s = fmaf(v, v, s); }
    __syncthreads();
    red[tid] = s;
    __syncthreads();
    for (int off = 128; off > 0; off >>= 1) {
        if (tid < off) red[tid] += red[tid + off];
        __syncthreads();
    }
    return red[0];
}

// -------- kernel 2: router MLP + noise + topk + l2 + lb + analytic gate ----
__global__ __launch_bounds__(256) void router_gate_kernel(
    const float* __restrict__ x,
    const float* __restrict__ W1, const float* __restrict__ b1,
    const float* __restrict__ W2, const float* __restrict__ b2,
    const float* __restrict__ W3, const float* __restrict__ b3,
    const float* __restrict__ W4, const float* __restrict__ b4,
    const float* __restrict__ Wu, const float* __restrict__ bu,
    const float* __restrict__ Wc, const float* __restrict__ bc,
    const float* __restrict__ cb,
    float* __restrict__ ws, float* __restrict__ out) {
    __shared__ float pooled[Bn * Cn];
    __shared__ float h1[Bn * HIDn];
    __shared__ float h2[Bn * HIDn];
    __shared__ float h3[Bn * 64];
    __shared__ float feat[Bn * 64];
    __shared__ float scores[Bn * Un];
    __shared__ float noise[64];
    __shared__ float red[256];
    __shared__ int topi[Bn * 2];
    __shared__ float bsum[Un];
    __shared__ float gsum_sh[16];
    __shared__ float gate_sh[Bn * Un];
    int tid = threadIdx.x;

    // ---- reduce w9 partials (64 x 1152 -> 8 x 1152), coalesced ----
    for (int i = tid; i < 9216; i += 256) {
        int u = i / 1152, e = i - u * 1152;
        float s = 0.f;
        #pragma unroll
        for (int gg = 0; gg < 8; ++gg)
            s += ws[WS_W9P + ((u << 3) + gg) * 1152 + e];
        ws[WS_W9 + i] = s;
    }

    for (int i = tid; i < Bn * Cn; i += 256) pooled[i] = ws[WS_POOLED + i];
    __syncthreads();

    for (int i = tid; i < Bn * HIDn; i += 256) {
        int b = i / HIDn, j = i % HIDn;
        float s = b1[j];
        const float* wr = W1 + j * Cn;
        for (int k = 0; k < Cn; ++k) s = fmaf(pooled[b * Cn + k], wr[k], s);
        h1[i] = fmaxf(s, 0.f);
    }
    __syncthreads();
    for (int i = tid; i < Bn * HIDn; i += 256) {
        int b = i / HIDn, j = i % HIDn;
        float s = b2[j];
        const float* wr = W2 + j * HIDn;
        for (int k = 0; k < HIDn; ++k) s = fmaf(h1[b * HIDn + k], wr[k], s);
        h2[i] = fmaxf(s, 0.f);
    }
    __syncthreads();
    for (int i = tid; i < Bn * 64; i += 256) {
        int b = i / 64, j = i % 64;
        float s = b3[j];
        const float* wr = W3 + j * HIDn;
        for (int k = 0; k < HIDn; ++k) s = fmaf(h2[b * HIDn + k], wr[k], s);
        h3[i] = fmaxf(s, 0.f);
    }
    __syncthreads();
    for (int i = tid; i < Bn * 64; i += 256) {
        int b = i / 64, j = i % 64;
        float s = b4[j];
        const float* wr = W4 + j * 64;
        for (int k = 0; k < 64; ++k) s = fmaf(h3[b * 64 + k], wr[k], s);
        feat[i] = s;
    }
    __syncthreads();
    if (tid < 64) noise[tid] = jax_noise_elem(tid);
    if (tid < Bn * Un) {
        int b = tid / Un, u = tid % Un;
        float s = bu[u];
        const float* wr = Wu + u * 64;
        for (int k = 0; k < 64; ++k) s = fmaf(feat[b * 64 + k], wr[k], s);
        scores[tid] = s;
    }
    for (int i = tid; i < Bn * Ln; i += 256) {
        int b = i / Ln, j = i % Ln;
        float s = bc[j];
        const float* wr = Wc + j * 64;
        for (int k = 0; k < 64; ++k) s = fmaf(feat[b * 64 + k], wr[k], s);
        out[OUT_CLS + i] = s;
    }
    __syncthreads();
    if (tid < Bn * Un) scores[tid] += noise[tid];
    __syncthreads();
    if (tid < Bn) {
        int b = tid;
        float best = -1e30f; int bi = 0;
        for (int u = 0; u < Un; ++u) {
            float v = scores[b * Un + u];
            if (v > best) { best = v; bi = u; }
        }
        float best2 = -1e30f; int bi2 = 0;
        for (int u = 0; u < Un; ++u) {
            if (u == bi) continue;
            float v = scores[b * Un + u];
            if (v > best2) { best2 = v; bi2 = u; }
        }
        topi[b * 2] = bi;
        topi[b * 2 + 1] = bi2;
        ((int*)ws)[WS_TOPI + b * 2] = bi;
        ((int*)ws)[WS_TOPI + b * 2 + 1] = bi2;
        out[OUT_TOPI + b * 2] = (float)bi;
        out[OUT_TOPI + b * 2 + 1] = (float)bi2;
    }
    __syncthreads();
    if (tid == 0) {
        int cnt[Un];
        for (int u = 0; u < Un; ++u) cnt[u] = 0;
        for (int i = 0; i < Bn * 2; ++i) cnt[topi[i]]++;
        float lb = 0.f;
        for (int u = 0; u < Un; ++u) {
            float d = (float)cnt[u] * (1.f / 16.f) - 0.125f;
            lb += d * d;
        }
        out[OUT_LB] = lb * (1.f / Un);
    }
    float l2 = 0.f;
    l2 += sqrtf(block_sumsq(W1, HIDn * Cn, red));
    l2 += sqrtf(block_sumsq(b1, HIDn, red));
    l2 += sqrtf(block_sumsq(W2, HIDn * HIDn, red));
    l2 += sqrtf(block_sumsq(b2, HIDn, red));
    l2 += sqrtf(block_sumsq(W3, 64 * HIDn, red));
    l2 += sqrtf(block_sumsq(b3, 64, red));
    l2 += sqrtf(block_sumsq(W4, 64 * 64, red));
    l2 += sqrtf(block_sumsq(b4, 64, red));
    l2 += sqrtf(block_sumsq(Wu, Un * 64, red));
    l2 += sqrtf(block_sumsq(bu, Un, red));
    l2 += sqrtf(block_sumsq(Wc, Ln * 64, red));
    l2 += sqrtf(block_sumsq(bc, Ln, red));
    if (tid == 0) out[OUT_L2] = 0.01f * l2;
    __syncthreads();

    // ---- analytic gate from border strips ----
    if (tid < Un) {
        float s = 0.f;
        for (int c = 0; c < Cn; ++c) s += cb[tid * Cn + c];
        bsum[tid] = s;
    }
    __syncthreads();
    {
        int p = tid >> 4, j = tid & 15;
        int b = p >> 1, k = p & 1;
        int u = topi[b * 2 + k];
        float partial = 0.f;
        for (int cin = j; cin < Cn; cin += 16) {
            const float* st = ws + WS_STR + (b * Cn + cin) * 5;
            float S = st[0], R0 = st[1], R63 = st[2], C0 = st[3], C63 = st[4];
            const float* xp = x + ((size_t)b * Cn + cin) * HWn;
            float c00 = xp[0], c0r = xp[63], cb0 = xp[4032], cbr = xp[4095];
            const float* w9 = ws + WS_W9 + (u * Cn + cin) * 9;
            float Rex[3] = {R63, 0.f, R0};
            float Cex[3] = {C63, 0.f, C0};
            float crn[3][3] = {{cbr, 0.f, cb0}, {0.f, 0.f, 0.f}, {c0r, 0.f, c00}};
            #pragma unroll
            for (int ky = 0; ky < 3; ++ky)
                #pragma unroll
                for (int kx = 0; kx < 3; ++kx) {
                    float T = S - Rex[ky] - Cex[kx] + crn[ky][kx];
                    partial = fmaf(w9[ky * 3 + kx], T, partial);
                }
        }
        #pragma unroll
        for (int off = 8; off > 0; off >>= 1)
            partial += __shfl_down(partial, off, 16);
        if (j == 0) gsum_sh[p] = partial;
    }
    __syncthreads();
    if (tid < Bn) {
        int b2 = tid;
        int s0 = topi[b2 * 2], s1 = topi[b2 * 2 + 1];
        float lg[Un];
        for (int u2 = 0; u2 < Un; ++u2) lg[u2] = bsum[u2] * (1.0f / Cn);
        lg[s0] += gsum_sh[b2 * 2] * (1.0f / (Cn * HWn));
        lg[s1] += gsum_sh[b2 * 2 + 1] * (1.0f / (Cn * HWn));
        float m = -1e30f;
        for (int u2 = 0; u2 < Un; ++u2) m = fmaxf(m, lg[u2]);
        float den = 0.f, e[Un];
        for (int u2 = 0; u2 < Un; ++u2) { e[u2] = expf(lg[u2] - m); den += e[u2]; }
        float inv = 1.0f / den;
        for (int u2 = 0; u2 < Un; ++u2) gate_sh[b2 * Un + u2] = e[u2] * inv;
        ws[WS_GSEL + b2 * 2] = gate_sh[b2 * Un + s0];
        ws[WS_GSEL + b2 * 2 + 1] = gate_sh[b2 * Un + s1];
    }
    __syncthreads();
    for (int i = tid; i < Bn * Cn; i += 256) {
        int b2 = i >> 7, c = i & 127;
        float s = 0.f;
        for (int u2 = 0; u2 < Un; ++u2)
            s = fmaf(gate_sh[b2 * Un + u2], cb[u2 * Cn + c], s);
        ws[WS_BIASC + i] = s;
    }
}

// -------- kernel 3: gate-combined weights -> bf16 [b][cout][tap][cin] ------
// block (b, cout-group of 4); contiguous row reads + LDS transpose
__global__ __launch_bounds__(256) void wprep_kernel(const float* __restrict__ cw,
                                                    float* __restrict__ ws) {
    int bid = blockIdx.x;            // 256 blocks
    int b = bid >> 5, g = bid & 31;
    const int* topi = (const int*)ws + WS_TOPI;
    int u0 = topi[b * 2], u1 = topi[b * 2 + 1];
    float g0 = ws[WS_GSEL + b * 2], g1 = ws[WS_GSEL + b * 2 + 1];
    __shared__ float lds[1152];
    unsigned short* wc = (unsigned short*)(ws + WS_WCOMB);
    int tid = threadIdx.x;
    for (int co = 0; co < 4; ++co) {
        int cout = g * 4 + co;
        const float* r0 = cw + ((size_t)u0 * 128 + cout) * 1152;
        const float* r1 = cw + ((size_t)u1 * 128 + cout) * 1152;
        if (co) __syncthreads();
        #pragma unroll
        for (int i = 0; i < 5; ++i) {
            int e = tid + i * 256;
            if (e < 1152) lds[e] = g0 * r0[e] + g1 * r1[e];
        }
        __syncthreads();
        #pragma unroll
        for (int i = 0; i < 3; ++i) {
            int p = tid + i * 256;           // 576 = 9 taps x 64 cin-pairs
            if (p < 576) {
                int tap = p >> 6, cp = p & 63;
                unsigned lo = f2bf(lds[(2 * cp) * 9 + tap]);
                unsigned hi = f2bf(lds[(2 * cp + 1) * 9 + tap]);
                *(unsigned*)(wc + ((((size_t)(b * 128 + cout) * 9 + tap) << 7)
                                   + 2 * cp)) = lo | (hi << 16);
            }
        }
    }
}

// -------- kernel 4: MFMA implicit-GEMM conv + gated combine ----------------
// block = (b[8], row y[64]); 128 threads = 2 waves (cout halves 0-63 / 64-127)
__global__ __launch_bounds__(128) void conv_mfma_kernel(
    const float* __restrict__ wsf, float* __restrict__ out) {
    const unsigned short* __restrict__ xt = (const unsigned short*)(wsf + WS_XT);
    const unsigned short* __restrict__ wc = (const unsigned short*)(wsf + WS_WCOMB);

    int bid = blockIdx.x;
    int b = bid >> 6, y = bid & 63;
    int tid = threadIdx.x;
    int wave = tid >> 6, lane = tid & 63;
    int quad = lane >> 4, l15 = lane & 15;
    int m0 = wave << 6;

    __shared__ __align__(16) unsigned short xs[198 * 40];

    f32x4 acc[4][4];
    #pragma unroll
    for (int mt = 0; mt < 4; ++mt)
        #pragma unroll
        for (int nt = 0; nt < 4; ++nt)
            acc[mt][nt] = (f32x4){0.f, 0.f, 0.f, 0.f};

    int ldsrd = l15 * 80 + quad * 16;

    for (int chunk = 0; chunk < 4; ++chunk) {
        if (chunk) __syncthreads();
        #pragma unroll
        for (int i = 0; i < 7; ++i) {
            int o = tid + i * 128;
            if (o < 792) {
                int px = o >> 2, part = o & 3;
                int r3 = px / 66;
                int col = px - r3 * 66;
                int ry = y + r3 - 1;
                int gx = col - 1;
                uint4 v = {0u, 0u, 0u, 0u};
                if ((unsigned)ry < 64u && (unsigned)gx < 64u) {
                    v = *(const uint4*)(xt +
                        ((((size_t)b * 64 + ry) * 64 + gx) << 7) +
                        (chunk << 5) + (part << 3));
                }
                *(uint4*)((char*)xs + px * 80 + part * 16) = v;
            }
        }
        __syncthreads();
        #pragma unroll
        for (int tap = 0; tap < 9; ++tap) {
            const int dy = tap / 3, dx = tap % 3;
            bf16x8 af[4];
            #pragma unroll
            for (int mt = 0; mt < 4; ++mt) {
                int cout = m0 + mt * 16 + l15;
                af[mt] = *(const bf16x8*)(wc +
                    (((size_t)(b * 128 + cout) * 9 + tap) << 7) +
                    (chunk << 5) + (quad << 3));
            }
            bf16x8 bfr[4];
            #pragma unroll
            for (int nt = 0; nt < 4; ++nt) {
                int off = (dy * 66 + dx + nt * 16) * 80;
                bfr[nt] = *(const bf16x8*)((char*)xs + ldsrd + off);
            }
            #pragma unroll
            for (int mt = 0; mt < 4; ++mt)
                #pragma unroll
                for (int nt = 0; nt < 4; ++nt)
                    acc[mt][nt] = __builtin_amdgcn_mfma_f32_16x16x32_bf16(
                        af[mt], bfr[nt], acc[mt][nt], 0, 0, 0);
        }
    }

    #pragma unroll
    for (int mt = 0; mt < 4; ++mt) {
        #pragma unroll
        for (int r = 0; r < 4; ++r) {
            int c = m0 + mt * 16 + (quad << 2) + r;
            float bias = wsf[WS_BIASC + (b << 7) + c];
            size_t rowb = (((size_t)b * 128 + c) << 12) + (y << 6);
            #pragma unroll
            for (int nt = 0; nt < 4; ++nt)
                out[rowb + nt * 16 + l15] = acc[mt][nt][r] + bias;
        }
    }
}

extern "C" void kernel_launch(void* const* d_in, const int* in_sizes, int n_in,
                              void* d_out, int out_size, void* d_ws, size_t ws_size,
                              hipStream_t stream) {
    const float* x  = (const float*)d_in[0];
    const float* W1 = (const float*)d_in[1];
    const float* b1 = (const float*)d_in[2];
    const float* W2 = (const float*)d_in[3];
    const float* b2 = (const float*)d_in[4];
    const float* W3 = (const float*)d_in[5];
    const float* b3 = (const float*)d_in[6];
    const float* W4 = (const float*)d_in[7];
    const float* b4 = (const float*)d_in[8];
    const float* Wu = (const float*)d_in[9];
    const float* bu = (const float*)d_in[10];
    const float* Wc = (const float*)d_in[11];
    const float* bc = (const float*)d_in[12];
    const float* cw = (const float*)d_in[13];
    const float* cb = (const float*)d_in[14];
    float* out = (float*)d_out;
    float* ws  = (float*)d_ws;

    prep_kernel<<<1600, 256, 0, stream>>>(x, cw, ws);
    router_gate_kernel<<<1, 256, 0, stream>>>(x, W1, b1, W2, b2, W3, b3, W4, b4,
                                              Wu, bu, Wc, bc, cb, ws, out);
    wprep_kernel<<<256, 256, 0, stream>>>(cw, ws);
    conv_mfma_kernel<<<512, 128, 0, stream>>>(ws, out);
}